// Round 1
// baseline (15199.713 us; speedup 1.0000x reference)
//
#include <hip/hip_runtime.h>

#define NN 100000
#define NMC 128
#define SS 6
#define EE 100000
#define ELR 30000
#define LLAYERS 4

// ---------------------------------------------------------------------------
// k_stem1: out[n][o] = relu(w1[o][0]*x[n][0] + w1[o][1]*x[n][1] + b1[o])
// ---------------------------------------------------------------------------
__global__ __launch_bounds__(256) void k_stem1(
    const float* __restrict__ x2, const float* __restrict__ w1,
    const float* __restrict__ b1, float* __restrict__ out)
{
  int64_t i = (int64_t)blockIdx.x * blockDim.x + threadIdx.x;
  const int64_t total = (int64_t)NN * NMC;
  const int64_t stride = (int64_t)gridDim.x * blockDim.x;
  for (; i < total; i += stride) {
    const int n = (int)(i >> 7);
    const int o = (int)(i & 127);
    const float v = w1[2*o] * x2[2*n] + w1[2*o+1] * x2[2*n+1] + b1[o];
    out[i] = fmaxf(v, 0.f);
  }
}

// ---------------------------------------------------------------------------
// k_matvec: out[u[e]][:] (+)= X[v[e]][:] @ W.T    (W is [128][128], W[o][c])
// Each wave keeps one 64-row half of W in 128 VGPRs. Waves are paired:
// wave pair shares one staged x row in LDS; half 0 computes outputs 0..63,
// half 1 computes 64..127. uidx/vidx == nullptr means identity (dense GEMM).
// ATOMIC selects scatter-add (unsafeAtomicAdd -> global_atomic_add_f32)
// vs direct store.
// ---------------------------------------------------------------------------
template<bool ATOMIC>
__global__ __launch_bounds__(256) void k_matvec(
    const float* __restrict__ X, const float* __restrict__ W,
    const int* __restrict__ uidx, const int* __restrict__ vidx,
    float* __restrict__ out, int nE)
{
  __shared__ float xbuf[2][NMC];
  const int t = threadIdx.x;
  const int lane = t & 63;
  const int wv = t >> 6;        // 0..3
  const int half = wv & 1;      // output half
  const int pair = wv >> 1;     // 0..1 (shared x slot)
  const int o = half * 64 + lane;

  // W row for my output channel, held in registers for the whole launch.
  float w[NMC];
  #pragma unroll
  for (int c = 0; c < NMC; c += 4) {
    const float4 wc = *(const float4* __restrict__)&W[o * NMC + c];
    w[c] = wc.x; w[c+1] = wc.y; w[c+2] = wc.z; w[c+3] = wc.w;
  }

  const int nW = gridDim.x * 2;               // edge workers (wave pairs)
  const int ew0 = blockIdx.x * 2 + pair;
  const int nIter = (nE + nW - 1) / nW;       // uniform trip count (barrier-safe)

  for (int it = 0; it < nIter; ++it) {
    const int e = ew0 + it * nW;
    const bool act = (e < nE);
    if (act && half == 0) {
      const int v = vidx ? vidx[e] : e;
      const float2 xv = *(const float2* __restrict__)&X[(int64_t)v * NMC + 2 * lane];
      xbuf[pair][2*lane]   = xv.x;
      xbuf[pair][2*lane+1] = xv.y;
    }
    __syncthreads();
    if (act) {
      float a0 = 0.f, a1 = 0.f, a2 = 0.f, a3 = 0.f;
      #pragma unroll
      for (int c = 0; c < NMC; c += 4) {
        const float4 xv = *(const float4*)&xbuf[pair][c];  // broadcast read
        a0 += w[c]   * xv.x;
        a1 += w[c+1] * xv.y;
        a2 += w[c+2] * xv.z;
        a3 += w[c+3] * xv.w;
      }
      const float acc = (a0 + a1) + (a2 + a3);
      const int u = uidx ? uidx[e] : e;
      if (ATOMIC) {
        unsafeAtomicAdd(&out[(int64_t)u * NMC + o], acc);
      } else {
        out[(int64_t)u * NMC + o] = acc;
      }
    }
    __syncthreads();   // protect xbuf from next iteration's overwrite
  }
}

// ---------------------------------------------------------------------------
// k_gn: in-place per-row GroupNorm(1 group over 128 ch), optional ReLU.
// One wave per node; lane owns channels 2*lane, 2*lane+1.
// ---------------------------------------------------------------------------
template<bool RELU>
__global__ __launch_bounds__(256) void k_gn(
    float* __restrict__ X, const float* __restrict__ gw, const float* __restrict__ gb)
{
  const int lane = threadIdx.x & 63;
  int n0 = (blockIdx.x * blockDim.x + threadIdx.x) >> 6;
  const int nWv = (gridDim.x * blockDim.x) >> 6;
  const float c0 = gw[2*lane], c1 = gw[2*lane+1];
  const float d0 = gb[2*lane], d1 = gb[2*lane+1];
  for (int n = n0; n < NN; n += nWv) {
    float2 x = *(float2*)&X[(int64_t)n * NMC + 2*lane];
    float s  = x.x + x.y;
    float s2 = x.x*x.x + x.y*x.y;
    #pragma unroll
    for (int off = 32; off >= 1; off >>= 1) {
      s  += __shfl_xor(s, off);
      s2 += __shfl_xor(s2, off);
    }
    const float mu = s * (1.f/128.f);
    const float rs = rsqrtf(s2*(1.f/128.f) - mu*mu + 1e-5f);
    float y0 = (x.x - mu)*rs*c0 + d0;
    float y1 = (x.y - mu)*rs*c1 + d1;
    if (RELU) { y0 = fmaxf(y0, 0.f); y1 = fmaxf(y1, 0.f); }
    *(float2*)&X[(int64_t)n * NMC + 2*lane] = make_float2(y0, y1);
  }
}

// ---------------------------------------------------------------------------
// k_combine (stem tail): feat = relu(fi + fs); res = feat.
// fi lives in `res`, fs lives in `feat` on entry.
// ---------------------------------------------------------------------------
__global__ __launch_bounds__(256) void k_combine(
    float* __restrict__ feat, float* __restrict__ res)
{
  const int64_t total4 = (int64_t)NN * NMC / 4;
  int64_t i = (int64_t)blockIdx.x * blockDim.x + threadIdx.x;
  const int64_t stride = (int64_t)gridDim.x * blockDim.x;
  float4* f4 = (float4*)feat;
  float4* r4 = (float4*)res;
  for (; i < total4; i += stride) {
    const float4 a = r4[i];
    const float4 b = f4[i];
    float4 y;
    y.x = fmaxf(a.x + b.x, 0.f);
    y.y = fmaxf(a.y + b.y, 0.f);
    y.z = fmaxf(a.z + b.z, 0.f);
    y.w = fmaxf(a.w + b.w, 0.f);
    f4[i] = y;
    r4[i] = y;
  }
}

// ---------------------------------------------------------------------------
// k_epilogue: feat = relu(GN(feat) + res); res = feat.  (feat holds X@ctr2_w.T)
// ---------------------------------------------------------------------------
__global__ __launch_bounds__(256) void k_epilogue(
    float* __restrict__ feat, float* __restrict__ res,
    const float* __restrict__ gw, const float* __restrict__ gb)
{
  const int lane = threadIdx.x & 63;
  int n0 = (blockIdx.x * blockDim.x + threadIdx.x) >> 6;
  const int nWv = (gridDim.x * blockDim.x) >> 6;
  const float c0 = gw[2*lane], c1 = gw[2*lane+1];
  const float d0 = gb[2*lane], d1 = gb[2*lane+1];
  for (int n = n0; n < NN; n += nWv) {
    const int64_t base = (int64_t)n * NMC + 2*lane;
    float2 x = *(float2*)&feat[base];
    float s  = x.x + x.y;
    float s2 = x.x*x.x + x.y*x.y;
    #pragma unroll
    for (int off = 32; off >= 1; off >>= 1) {
      s  += __shfl_xor(s, off);
      s2 += __shfl_xor(s2, off);
    }
    const float mu = s * (1.f/128.f);
    const float rs = rsqrtf(s2*(1.f/128.f) - mu*mu + 1e-5f);
    const float2 r = *(float2*)&res[base];
    const float y0 = fmaxf((x.x - mu)*rs*c0 + d0 + r.x, 0.f);
    const float y1 = fmaxf((x.y - mu)*rs*c1 + d1 + r.y, 0.f);
    *(float2*)&feat[base] = make_float2(y0, y1);
    *(float2*)&res[base]  = make_float2(y0, y1);
  }
}

// ---------------------------------------------------------------------------
extern "C" void kernel_launch(void* const* d_in, const int* in_sizes, int n_in,
                              void* d_out, int out_size, void* d_ws, size_t ws_size,
                              hipStream_t stream)
{
  const float* ctrs     = (const float*)d_in[0];
  const float* feats    = (const float*)d_in[1];
  const int*   pre_u    = (const int*)d_in[2];
  const int*   pre_v    = (const int*)d_in[3];
  const int*   suc_u    = (const int*)d_in[4];
  const int*   suc_v    = (const int*)d_in[5];
  const int*   left_u   = (const int*)d_in[6];
  const int*   left_v   = (const int*)d_in[7];
  const int*   right_u  = (const int*)d_in[8];
  const int*   right_v  = (const int*)d_in[9];
  const float* in1_w    = (const float*)d_in[10];
  const float* in1_b    = (const float*)d_in[11];
  const float* in2_w    = (const float*)d_in[12];
  const float* in_gn_w  = (const float*)d_in[13];
  const float* in_gn_b  = (const float*)d_in[14];
  const float* seg1_w   = (const float*)d_in[15];
  const float* seg1_b   = (const float*)d_in[16];
  const float* seg2_w   = (const float*)d_in[17];
  const float* seg_gn_w = (const float*)d_in[18];
  const float* seg_gn_b = (const float*)d_in[19];
  const float* ctr_w    = (const float*)d_in[20];
  const float* pre_w    = (const float*)d_in[21];
  const float* suc_w    = (const float*)d_in[22];
  const float* left_w   = (const float*)d_in[23];
  const float* right_w  = (const float*)d_in[24];
  const float* norm_w   = (const float*)d_in[25];
  const float* norm_b   = (const float*)d_in[26];
  const float* ctr2_w   = (const float*)d_in[27];
  const float* ctr2_gn_w= (const float*)d_in[28];
  const float* ctr2_gn_b= (const float*)d_in[29];

  float* feat = (float*)d_out;                    // [N,128], final answer
  float* temp = (float*)d_ws;                     // [N,128] scatter accumulator
  float* res  = temp + (size_t)NN * NMC;          // [N,128] residual

  // ---- stem ----
  // fi path: h1 -> temp ; fi_pre -> res ; GN in place
  k_stem1<<<2048, 256, 0, stream>>>(ctrs, in1_w, in1_b, temp);
  k_matvec<false><<<1024, 256, 0, stream>>>(temp, in2_w, nullptr, nullptr, res, NN);
  k_gn<false><<<1024, 256, 0, stream>>>(res, in_gn_w, in_gn_b);
  // fs path: h1 -> temp ; fs_pre -> feat ; GN in place
  k_stem1<<<2048, 256, 0, stream>>>(feats, seg1_w, seg1_b, temp);
  k_matvec<false><<<1024, 256, 0, stream>>>(temp, seg2_w, nullptr, nullptr, feat, NN);
  k_gn<false><<<1024, 256, 0, stream>>>(feat, seg_gn_w, seg_gn_b);
  // feat = relu(fi + fs); res = feat
  k_combine<<<2048, 256, 0, stream>>>(feat, res);

  // ---- fusion layers ----
  for (int i = 0; i < LLAYERS; ++i) {
    const size_t wb = (size_t)i * NMC * NMC;
    // temp = feat @ ctr_w[i].T
    k_matvec<false><<<1024, 256, 0, stream>>>(feat, ctr_w + wb, nullptr, nullptr, temp, NN);
    // multi-scale pre/suc scatter-adds
    for (int k = 0; k < SS; ++k) {
      const size_t wsk = ((size_t)(i * SS + k)) * NMC * NMC;
      k_matvec<true><<<1024, 256, 0, stream>>>(feat, pre_w + wsk,
          pre_u + (size_t)k * EE, pre_v + (size_t)k * EE, temp, EE);
      k_matvec<true><<<1024, 256, 0, stream>>>(feat, suc_w + wsk,
          suc_u + (size_t)k * EE, suc_v + (size_t)k * EE, temp, EE);
    }
    k_matvec<true><<<512, 256, 0, stream>>>(feat, left_w + wb, left_u, left_v, temp, ELR);
    k_matvec<true><<<512, 256, 0, stream>>>(feat, right_w + wb, right_u, right_v, temp, ELR);
    // feat_mid = relu(GN(temp)) in place
    k_gn<true><<<1024, 256, 0, stream>>>(temp, norm_w + i*NMC, norm_b + i*NMC);
    // feat = feat_mid @ ctr2_w[i].T   (feat buffer is dead here, reuse it)
    k_matvec<false><<<1024, 256, 0, stream>>>(temp, ctr2_w + wb, nullptr, nullptr, feat, NN);
    // feat = relu(GN(feat) + res); res = feat
    k_epilogue<<<1024, 256, 0, stream>>>(feat, res, ctr2_gn_w + i*NMC, ctr2_gn_b + i*NMC);
  }
}

// Round 2
// 2799.536 us; speedup vs baseline: 5.4294x; 5.4294x over previous
//
#include <hip/hip_runtime.h>

#define NN 100000
#define NMC 128
#define SS 6
#define EE 100000
#define ELR 30000
#define LLAYERS 4

typedef short s16x8 __attribute__((ext_vector_type(8)));
typedef float f32x4 __attribute__((ext_vector_type(4)));

// f32 -> bf16 (RNE via HW cvt), bit pattern in a short
__device__ inline short f2bf(float f) {
  __bf16 h = (__bf16)f;
  return __builtin_bit_cast(short, h);
}
__device__ inline s16x8 cvt8(float4 a, float4 b) {
  s16x8 r;
  r[0]=f2bf(a.x); r[1]=f2bf(a.y); r[2]=f2bf(a.z); r[3]=f2bf(a.w);
  r[4]=f2bf(b.x); r[5]=f2bf(b.y); r[6]=f2bf(b.z); r[7]=f2bf(b.w);
  return r;
}

// ---------------------------------------------------------------------------
// k_stem1: out[n][o] = relu(w1[o][0]*x[n][0] + w1[o][1]*x[n][1] + b1[o])
// ---------------------------------------------------------------------------
__global__ __launch_bounds__(256) void k_stem1(
    const float* __restrict__ x2, const float* __restrict__ w1,
    const float* __restrict__ b1, float* __restrict__ out)
{
  int64_t i = (int64_t)blockIdx.x * blockDim.x + threadIdx.x;
  const int64_t total = (int64_t)NN * NMC;
  const int64_t stride = (int64_t)gridDim.x * blockDim.x;
  for (; i < total; i += stride) {
    const int n = (int)(i >> 7);
    const int o = (int)(i & 127);
    const float v = w1[2*o] * x2[2*n] + w1[2*o+1] * x2[2*n+1] + b1[o];
    out[i] = fmaxf(v, 0.f);
  }
}

// ---------------------------------------------------------------------------
// k_dense<EPI>: Out = X @ W.T  over N=100000 rows, bf16 MFMA, f32 accum.
//   EPI=0: store raw to out
//   EPI=1: GroupNorm(out) with gw/gb, store to out
//   EPI=3: y = relu(GN(out) + res); store y to out AND res
// Block = 4 waves; tile = 32 rows x 128 cols. Wave w: m-block = w&1 (16 rows),
// n-group = w>>1 (cols 64*ng .. +63 as 4 x 16-col blocks).
// B fragments (W^T) preloaded to 64 VGPRs once per block, transpose folded
// into addressing: lane needs W[n][k..k+7] which is contiguous.
// MFMA 16x16x32 layouts: A row=lane&15, k=8*(lane>>4)+i (+32*ks);
// B col=lane&15, same k; C/D col=lane&15, row=4*(lane>>4)+reg.
// ---------------------------------------------------------------------------
template<int EPI>
__global__ __launch_bounds__(256) void k_dense(
    const float* __restrict__ X, const float* __restrict__ W,
    float* __restrict__ out, const float* __restrict__ gw,
    const float* __restrict__ gb, float* __restrict__ res)
{
  __shared__ float cl[32 * 129];   // padded: stride 129 breaks bank aliasing
  const int lane = threadIdx.x & 63;
  const int w = threadIdx.x >> 6;
  const int m = w & 1, ng = w >> 1;
  const int lr = lane & 15, lg = lane >> 4;

  s16x8 B[4][4];
  #pragma unroll
  for (int t4 = 0; t4 < 4; ++t4)
    #pragma unroll
    for (int ks = 0; ks < 4; ++ks) {
      const int n = 64*ng + 16*t4 + lr;
      const int k = 32*ks + 8*lg;
      const float4* p = (const float4*)&W[n * NMC + k];
      B[t4][ks] = cvt8(p[0], p[1]);
    }

  float gwc0 = 0.f, gwc1 = 0.f, gbc0 = 0.f, gbc1 = 0.f;
  if (EPI) { gwc0 = gw[2*lane]; gwc1 = gw[2*lane+1];
             gbc0 = gb[2*lane]; gbc1 = gb[2*lane+1]; }

  const int nTiles = NN / 32;   // 3125, exact
  for (int tile = blockIdx.x; tile < nTiles; tile += gridDim.x) {
    const int row = tile*32 + 16*m + lr;
    s16x8 A[4];
    #pragma unroll
    for (int ks = 0; ks < 4; ++ks) {
      const float4* p = (const float4*)&X[(size_t)row * NMC + 32*ks + 8*lg];
      A[ks] = cvt8(p[0], p[1]);
    }
    f32x4 acc[4] = {};
    #pragma unroll
    for (int ks = 0; ks < 4; ++ks)
      #pragma unroll
      for (int t4 = 0; t4 < 4; ++t4)
        acc[t4] = __builtin_amdgcn_mfma_f32_16x16x32_bf16(A[ks], B[t4][ks], acc[t4], 0, 0, 0);

    if (EPI == 0) {
      #pragma unroll
      for (int j = 0; j < 4; ++j) {
        const int r = tile*32 + 16*m + 4*lg + j;
        #pragma unroll
        for (int t4 = 0; t4 < 4; ++t4)
          out[(size_t)r * NMC + 64*ng + 16*t4 + lr] = acc[t4][j];
      }
    } else {
      #pragma unroll
      for (int j = 0; j < 4; ++j) {
        const int r = 16*m + 4*lg + j;
        #pragma unroll
        for (int t4 = 0; t4 < 4; ++t4)
          cl[r * 129 + 64*ng + 16*t4 + lr] = acc[t4][j];
      }
      __syncthreads();
      #pragma unroll
      for (int rr = 0; rr < 8; ++rr) {
        const int r = rr*4 + w;               // wave handles rows w, w+4, ...
        const float x0 = cl[r*129 + 2*lane];
        const float x1 = cl[r*129 + 2*lane + 1];
        float s  = x0 + x1;
        float s2 = x0*x0 + x1*x1;
        #pragma unroll
        for (int off = 32; off >= 1; off >>= 1) {
          s  += __shfl_xor(s, off);
          s2 += __shfl_xor(s2, off);
        }
        const float mu = s * (1.f/128.f);
        const float rs = rsqrtf(s2*(1.f/128.f) - mu*mu + 1e-5f);
        float y0 = (x0 - mu)*rs*gwc0 + gbc0;
        float y1 = (x1 - mu)*rs*gwc1 + gbc1;
        const size_t base = (size_t)(tile*32 + r) * NMC + 2*lane;
        if (EPI == 3) {
          const float2 rv = *(const float2*)&res[base];
          y0 = fmaxf(y0 + rv.x, 0.f);
          y1 = fmaxf(y1 + rv.y, 0.f);
          *(float2*)&res[base] = make_float2(y0, y1);
        }
        *(float2*)&out[base] = make_float2(y0, y1);
      }
      __syncthreads();
    }
  }
}

// ---------------------------------------------------------------------------
// k_edge: ALL 14 edge-sets of one layer in one dispatch (blockIdx.y = set).
// temp[u[e]][:] += feat[v[e]][:] @ W_set.T   via bf16 MFMA, f32 atomics.
// Zero LDS, zero barriers: B frags in 64 VGPRs, A gathered straight from
// global, C scattered with unsafeAtomicAdd (global_atomic_add_f32).
// ---------------------------------------------------------------------------
__global__ __launch_bounds__(256) void k_edge(
    const float* __restrict__ feat, float* __restrict__ temp,
    const int* __restrict__ pre_u, const int* __restrict__ pre_v,
    const int* __restrict__ suc_u, const int* __restrict__ suc_v,
    const int* __restrict__ lu, const int* __restrict__ lv,
    const int* __restrict__ ru, const int* __restrict__ rv,
    const float* __restrict__ pre_w, const float* __restrict__ suc_w,
    const float* __restrict__ lw, const float* __restrict__ rw,
    int layer)
{
  const int s = blockIdx.y;   // 0..13
  const int* U; const int* V; const float* W; int nE;
  if (s < SS) {
    U = pre_u + s*EE; V = pre_v + s*EE;
    W = pre_w + ((size_t)(layer*SS + s)) * NMC * NMC; nE = EE;
  } else if (s < 2*SS) {
    const int k = s - SS;
    U = suc_u + k*EE; V = suc_v + k*EE;
    W = suc_w + ((size_t)(layer*SS + k)) * NMC * NMC; nE = EE;
  } else if (s == 2*SS) {
    U = lu; V = lv; W = lw + (size_t)layer * NMC * NMC; nE = ELR;
  } else {
    U = ru; V = rv; W = rw + (size_t)layer * NMC * NMC; nE = ELR;
  }

  const int lane = threadIdx.x & 63;
  const int w = threadIdx.x >> 6;
  const int m = w & 1, ng = w >> 1;
  const int lr = lane & 15, lg = lane >> 4;

  s16x8 B[4][4];
  #pragma unroll
  for (int t4 = 0; t4 < 4; ++t4)
    #pragma unroll
    for (int ks = 0; ks < 4; ++ks) {
      const int n = 64*ng + 16*t4 + lr;
      const int k = 32*ks + 8*lg;
      const float4* p = (const float4*)&W[n * NMC + k];
      B[t4][ks] = cvt8(p[0], p[1]);
    }

  const int nTiles = (nE + 31) >> 5;
  for (int tile = blockIdx.x; tile < nTiles; tile += gridDim.x) {
    const int e0 = tile * 32;
    const int er = e0 + 16*m + lr;                 // edge for my A row
    const int v = (er < nE) ? V[er] : 0;
    s16x8 A[4];
    #pragma unroll
    for (int ks = 0; ks < 4; ++ks) {
      const float4* p = (const float4*)&feat[(size_t)v * NMC + 32*ks + 8*lg];
      A[ks] = cvt8(p[0], p[1]);
    }
    f32x4 acc[4] = {};
    #pragma unroll
    for (int ks = 0; ks < 4; ++ks)
      #pragma unroll
      for (int t4 = 0; t4 < 4; ++t4)
        acc[t4] = __builtin_amdgcn_mfma_f32_16x16x32_bf16(A[ks], B[t4][ks], acc[t4], 0, 0, 0);

    #pragma unroll
    for (int j = 0; j < 4; ++j) {
      const int eo = e0 + 16*m + 4*lg + j;         // edge for this C row
      if (eo < nE) {
        const int u = U[eo];
        #pragma unroll
        for (int t4 = 0; t4 < 4; ++t4)
          unsafeAtomicAdd(&temp[(size_t)u * NMC + 64*ng + 16*t4 + lr], acc[t4][j]);
      }
    }
  }
}

// ---------------------------------------------------------------------------
// k_gn<RELU>: in-place per-row GroupNorm (mid-layer norm on temp)
// ---------------------------------------------------------------------------
template<bool RELU>
__global__ __launch_bounds__(256) void k_gn(
    float* __restrict__ X, const float* __restrict__ gw, const float* __restrict__ gb)
{
  const int lane = threadIdx.x & 63;
  int n0 = (blockIdx.x * blockDim.x + threadIdx.x) >> 6;
  const int nWv = (gridDim.x * blockDim.x) >> 6;
  const float c0 = gw[2*lane], c1 = gw[2*lane+1];
  const float d0 = gb[2*lane], d1 = gb[2*lane+1];
  for (int n = n0; n < NN; n += nWv) {
    float2 x = *(float2*)&X[(size_t)n * NMC + 2*lane];
    float s  = x.x + x.y;
    float s2 = x.x*x.x + x.y*x.y;
    #pragma unroll
    for (int off = 32; off >= 1; off >>= 1) {
      s  += __shfl_xor(s, off);
      s2 += __shfl_xor(s2, off);
    }
    const float mu = s * (1.f/128.f);
    const float rs = rsqrtf(s2*(1.f/128.f) - mu*mu + 1e-5f);
    float y0 = (x.x - mu)*rs*c0 + d0;
    float y1 = (x.y - mu)*rs*c1 + d1;
    if (RELU) { y0 = fmaxf(y0, 0.f); y1 = fmaxf(y1, 0.f); }
    *(float2*)&X[(size_t)n * NMC + 2*lane] = make_float2(y0, y1);
  }
}

// ---------------------------------------------------------------------------
// k_combine: feat = relu(fi + fs); res = feat. (fi in res, fs in feat)
// ---------------------------------------------------------------------------
__global__ __launch_bounds__(256) void k_combine(
    float* __restrict__ feat, float* __restrict__ res)
{
  const int64_t total4 = (int64_t)NN * NMC / 4;
  int64_t i = (int64_t)blockIdx.x * blockDim.x + threadIdx.x;
  const int64_t stride = (int64_t)gridDim.x * blockDim.x;
  float4* f4 = (float4*)feat;
  float4* r4 = (float4*)res;
  for (; i < total4; i += stride) {
    const float4 a = r4[i];
    const float4 b = f4[i];
    float4 y;
    y.x = fmaxf(a.x + b.x, 0.f);
    y.y = fmaxf(a.y + b.y, 0.f);
    y.z = fmaxf(a.z + b.z, 0.f);
    y.w = fmaxf(a.w + b.w, 0.f);
    f4[i] = y;
    r4[i] = y;
  }
}

// ---------------------------------------------------------------------------
extern "C" void kernel_launch(void* const* d_in, const int* in_sizes, int n_in,
                              void* d_out, int out_size, void* d_ws, size_t ws_size,
                              hipStream_t stream)
{
  const float* ctrs     = (const float*)d_in[0];
  const float* feats    = (const float*)d_in[1];
  const int*   pre_u    = (const int*)d_in[2];
  const int*   pre_v    = (const int*)d_in[3];
  const int*   suc_u    = (const int*)d_in[4];
  const int*   suc_v    = (const int*)d_in[5];
  const int*   left_u   = (const int*)d_in[6];
  const int*   left_v   = (const int*)d_in[7];
  const int*   right_u  = (const int*)d_in[8];
  const int*   right_v  = (const int*)d_in[9];
  const float* in1_w    = (const float*)d_in[10];
  const float* in1_b    = (const float*)d_in[11];
  const float* in2_w    = (const float*)d_in[12];
  const float* in_gn_w  = (const float*)d_in[13];
  const float* in_gn_b  = (const float*)d_in[14];
  const float* seg1_w   = (const float*)d_in[15];
  const float* seg1_b   = (const float*)d_in[16];
  const float* seg2_w   = (const float*)d_in[17];
  const float* seg_gn_w = (const float*)d_in[18];
  const float* seg_gn_b = (const float*)d_in[19];
  const float* ctr_w    = (const float*)d_in[20];
  const float* pre_w    = (const float*)d_in[21];
  const float* suc_w    = (const float*)d_in[22];
  const float* left_w   = (const float*)d_in[23];
  const float* right_w  = (const float*)d_in[24];
  const float* norm_w   = (const float*)d_in[25];
  const float* norm_b   = (const float*)d_in[26];
  const float* ctr2_w   = (const float*)d_in[27];
  const float* ctr2_gn_w= (const float*)d_in[28];
  const float* ctr2_gn_b= (const float*)d_in[29];

  float* feat = (float*)d_out;                    // [N,128], final answer
  float* temp = (float*)d_ws;                     // [N,128] scratch / accumulator
  float* res  = temp + (size_t)NN * NMC;          // [N,128] residual

  // ---- stems: Linear(2,128)+ReLU -> Linear(128,128) -> GN (fused) ----
  k_stem1<<<2048, 256, 0, stream>>>(ctrs, in1_w, in1_b, temp);
  k_dense<1><<<625, 256, 0, stream>>>(temp, in2_w, res, in_gn_w, in_gn_b, nullptr);
  k_stem1<<<2048, 256, 0, stream>>>(feats, seg1_w, seg1_b, temp);
  k_dense<1><<<625, 256, 0, stream>>>(temp, seg2_w, feat, seg_gn_w, seg_gn_b, nullptr);
  k_combine<<<2048, 256, 0, stream>>>(feat, res);

  // ---- fusion layers ----
  for (int i = 0; i < LLAYERS; ++i) {
    const size_t wb = (size_t)i * NMC * NMC;
    // temp = feat @ ctr_w[i].T
    k_dense<0><<<625, 256, 0, stream>>>(feat, ctr_w + wb, temp, nullptr, nullptr, nullptr);
    // all 14 edge-set scatter-GEMMs in one dispatch
    dim3 eg(256, 14);
    k_edge<<<eg, 256, 0, stream>>>(feat, temp,
        pre_u, pre_v, suc_u, suc_v, left_u, left_v, right_u, right_v,
        pre_w, suc_w, left_w, right_w, i);
    // temp = relu(GN(temp))
    k_gn<true><<<1024, 256, 0, stream>>>(temp, norm_w + i*NMC, norm_b + i*NMC);
    // feat = relu(GN(temp @ ctr2_w.T) + res); res = feat   (fused epilogue)
    k_dense<3><<<625, 256, 0, stream>>>(temp, ctr2_w + wb, feat,
        ctr2_gn_w + i*NMC, ctr2_gn_b + i*NMC, res);
  }
}

// Round 3
// 2799.375 us; speedup vs baseline: 5.4297x; 1.0001x over previous
//
#include <hip/hip_runtime.h>
#include <hip/hip_bf16.h>

#define NN 100000
#define NMC 128
#define SS 6
#define EE 100000
#define ELR 30000
#define LLAYERS 4

typedef short s16x8 __attribute__((ext_vector_type(8)));
typedef float f32x4 __attribute__((ext_vector_type(4)));

__device__ inline unsigned short f2bf(float f) {
  __bf16 h = (__bf16)f;
  return __builtin_bit_cast(unsigned short, h);
}
__device__ inline float bf2f(unsigned short u) {
  unsigned int b = ((unsigned int)u) << 16;
  return __builtin_bit_cast(float, b);
}
__device__ inline s16x8 cvt8(float4 a, float4 b) {
  s16x8 r;
  r[0]=(short)f2bf(a.x); r[1]=(short)f2bf(a.y); r[2]=(short)f2bf(a.z); r[3]=(short)f2bf(a.w);
  r[4]=(short)f2bf(b.x); r[5]=(short)f2bf(b.y); r[6]=(short)f2bf(b.z); r[7]=(short)f2bf(b.w);
  return r;
}
// HW packed bf16 atomic add (2 x bf16 per dword). Inline asm: guaranteed to
// assemble on gfx950; fire-and-forget (no return).
__device__ inline void pk_atomic_add_bf16(void* p, unsigned int packed) {
  asm volatile("global_atomic_pk_add_bf16 %0, %1, off" :: "v"(p), "v"(packed) : "memory");
}

// ---------------------------------------------------------------------------
// k_stem1b: outb[n][o] = relu(w1[o][:2] . x[n][:2] + b1[o]), bf16 out.
// Thread handles a column pair (4B packed store).
// ---------------------------------------------------------------------------
__global__ __launch_bounds__(256) void k_stem1b(
    const float* __restrict__ x2, const float* __restrict__ w1,
    const float* __restrict__ b1, __hip_bfloat16* __restrict__ outb)
{
  int64_t i = (int64_t)blockIdx.x * blockDim.x + threadIdx.x;
  const int64_t total = (int64_t)NN * 64;
  const int64_t stride = (int64_t)gridDim.x * blockDim.x;
  for (; i < total; i += stride) {
    const int n = (int)(i >> 6);
    const int o = (int)(i & 63) * 2;
    const float2 xv = ((const float2*)x2)[n];
    float v0 = fmaxf(w1[2*o]   * xv.x + w1[2*o+1] * xv.y + b1[o],   0.f);
    float v1 = fmaxf(w1[2*o+2] * xv.x + w1[2*o+3] * xv.y + b1[o+1], 0.f);
    const unsigned int packed = ((unsigned int)f2bf(v1) << 16) | f2bf(v0);
    *(unsigned int*)&outb[(size_t)n * NMC + o] = packed;
  }
}

// ---------------------------------------------------------------------------
// k_dense<EPI>: Out = Xb @ W.T over N rows; A in bf16, bf16 MFMA, f32 accum.
//   EPI=0: store bf16 to outb (paired-column packed stores)
//   EPI=1: GroupNorm -> store f32 to outf
//   EPI=3: y = relu(GN(acc) + res) -> store bf16 to outb AND f32 to res;
//          if wout, also store f32 y to outf (final output)
// Block: 4 waves, tile 32 rows x 128 cols. Wave w: m=w&1 (16 rows),
// ng=w>>1 (64-col group as 4 x 16-col blocks).
// MFMA 16x16x32 layouts: A row=lane&15, k=8*(lane>>4)+i (+32*ks);
// B col=lane&15 same k; C/D col=lane&15, row=4*(lane>>4)+reg.
// ---------------------------------------------------------------------------
template<int EPI>
__global__ __launch_bounds__(256) void k_dense(
    const __hip_bfloat16* __restrict__ Xb, const float* __restrict__ W,
    __hip_bfloat16* __restrict__ outb, float* __restrict__ outf,
    const float* __restrict__ gw, const float* __restrict__ gb,
    float* __restrict__ res, int wout)
{
  __shared__ float cl[32 * 129];
  const int lane = threadIdx.x & 63;
  const int w = threadIdx.x >> 6;
  const int m = w & 1, ng = w >> 1;
  const int lr = lane & 15, lg = lane >> 4;

  s16x8 B[4][4];
  #pragma unroll
  for (int t4 = 0; t4 < 4; ++t4)
    #pragma unroll
    for (int ks = 0; ks < 4; ++ks) {
      const int n = 64*ng + 16*t4 + lr;
      const int k = 32*ks + 8*lg;
      const float4* p = (const float4*)&W[n * NMC + k];
      B[t4][ks] = cvt8(p[0], p[1]);
    }

  float gwc0 = 0.f, gwc1 = 0.f, gbc0 = 0.f, gbc1 = 0.f;
  if (EPI) { gwc0 = gw[2*lane]; gwc1 = gw[2*lane+1];
             gbc0 = gb[2*lane]; gbc1 = gb[2*lane+1]; }

  const int nTiles = NN / 32;   // 3125, exact
  for (int tile = blockIdx.x; tile < nTiles; tile += gridDim.x) {
    const int row = tile*32 + 16*m + lr;
    s16x8 A[4];
    #pragma unroll
    for (int ks = 0; ks < 4; ++ks)
      A[ks] = *(const s16x8*)&Xb[(size_t)row * NMC + 32*ks + 8*lg];

    f32x4 acc[4] = {};
    #pragma unroll
    for (int ks = 0; ks < 4; ++ks)
      #pragma unroll
      for (int t4 = 0; t4 < 4; ++t4)
        acc[t4] = __builtin_amdgcn_mfma_f32_16x16x32_bf16(A[ks], B[t4][ks], acc[t4], 0, 0, 0);

    if (EPI == 0) {
      // paired-column packed bf16 stores: lane-pair exchanges via shfl_xor(1)
      #pragma unroll
      for (int j = 0; j < 4; ++j) {
        const int r = tile*32 + 16*m + 4*lg + j;
        #pragma unroll
        for (int t4 = 0; t4 < 4; ++t4) {
          const float other = __shfl_xor(acc[t4][j], 1);
          if ((lr & 1) == (t4 >> 1)) {        // even lanes: t4 0,1; odd: 2,3
            const int col0 = 64*ng + 16*t4 + (lr & ~1);
            const float lo = (lr & 1) ? other : acc[t4][j];
            const float hi = (lr & 1) ? acc[t4][j] : other;
            const unsigned int packed = ((unsigned int)f2bf(hi) << 16) | f2bf(lo);
            *(unsigned int*)&outb[(size_t)r * NMC + col0] = packed;
          }
        }
      }
    } else {
      #pragma unroll
      for (int j = 0; j < 4; ++j) {
        const int r = 16*m + 4*lg + j;
        #pragma unroll
        for (int t4 = 0; t4 < 4; ++t4)
          cl[r * 129 + 64*ng + 16*t4 + lr] = acc[t4][j];
      }
      __syncthreads();
      #pragma unroll
      for (int rr = 0; rr < 8; ++rr) {
        const int r = rr*4 + w;
        const float x0 = cl[r*129 + 2*lane];
        const float x1 = cl[r*129 + 2*lane + 1];
        float s  = x0 + x1;
        float s2 = x0*x0 + x1*x1;
        #pragma unroll
        for (int off = 32; off >= 1; off >>= 1) {
          s  += __shfl_xor(s, off);
          s2 += __shfl_xor(s2, off);
        }
        const float mu = s * (1.f/128.f);
        const float rs = rsqrtf(s2*(1.f/128.f) - mu*mu + 1e-5f);
        float y0 = (x0 - mu)*rs*gwc0 + gbc0;
        float y1 = (x1 - mu)*rs*gwc1 + gbc1;
        const int grow = tile*32 + r;
        const size_t base = (size_t)grow * NMC + 2*lane;
        if (EPI == 3) {
          const float2 rv = *(const float2*)&res[base];
          y0 = fmaxf(y0 + rv.x, 0.f);
          y1 = fmaxf(y1 + rv.y, 0.f);
          *(float2*)&res[base] = make_float2(y0, y1);
          const unsigned int packed = ((unsigned int)f2bf(y1) << 16) | f2bf(y0);
          *(unsigned int*)&outb[base] = packed;
          if (wout) *(float2*)&outf[base] = make_float2(y0, y1);
        } else {
          *(float2*)&outf[base] = make_float2(y0, y1);
        }
      }
      __syncthreads();
    }
  }
}

// ---------------------------------------------------------------------------
// k_edge: all 14 edge-sets of one layer in one dispatch (blockIdx.y = set).
// tempb[u[e]][:] += featb[v[e]][:] @ W_set.T ; bf16 gathers, bf16 MFMA,
// packed-bf16 atomics. Zero LDS, zero barriers.
// ---------------------------------------------------------------------------
__global__ __launch_bounds__(256) void k_edge(
    const __hip_bfloat16* __restrict__ featb, __hip_bfloat16* __restrict__ tempb,
    const int* __restrict__ pre_u, const int* __restrict__ pre_v,
    const int* __restrict__ suc_u, const int* __restrict__ suc_v,
    const int* __restrict__ lu, const int* __restrict__ lv,
    const int* __restrict__ ru, const int* __restrict__ rv,
    const float* __restrict__ pre_w, const float* __restrict__ suc_w,
    const float* __restrict__ lw, const float* __restrict__ rw,
    int layer)
{
  const int s = blockIdx.y;   // 0..13
  const int* U; const int* V; const float* W; int nE;
  if (s < SS) {
    U = pre_u + s*EE; V = pre_v + s*EE;
    W = pre_w + ((size_t)(layer*SS + s)) * NMC * NMC; nE = EE;
  } else if (s < 2*SS) {
    const int k = s - SS;
    U = suc_u + k*EE; V = suc_v + k*EE;
    W = suc_w + ((size_t)(layer*SS + k)) * NMC * NMC; nE = EE;
  } else if (s == 2*SS) {
    U = lu; V = lv; W = lw + (size_t)layer * NMC * NMC; nE = ELR;
  } else {
    U = ru; V = rv; W = rw + (size_t)layer * NMC * NMC; nE = ELR;
  }

  const int lane = threadIdx.x & 63;
  const int w = threadIdx.x >> 6;
  const int m = w & 1, ng = w >> 1;
  const int lr = lane & 15, lg = lane >> 4;

  s16x8 B[4][4];
  #pragma unroll
  for (int t4 = 0; t4 < 4; ++t4)
    #pragma unroll
    for (int ks = 0; ks < 4; ++ks) {
      const int n = 64*ng + 16*t4 + lr;
      const int k = 32*ks + 8*lg;
      const float4* p = (const float4*)&W[n * NMC + k];
      B[t4][ks] = cvt8(p[0], p[1]);
    }

  const int nTiles = (nE + 31) >> 5;
  for (int tile = blockIdx.x; tile < nTiles; tile += gridDim.x) {
    const int e0 = tile * 32;
    const int er = e0 + 16*m + lr;
    const int v = (er < nE) ? V[er] : 0;
    s16x8 A[4];
    #pragma unroll
    for (int ks = 0; ks < 4; ++ks)
      A[ks] = *(const s16x8*)&featb[(size_t)v * NMC + 32*ks + 8*lg];

    f32x4 acc[4] = {};
    #pragma unroll
    for (int ks = 0; ks < 4; ++ks)
      #pragma unroll
      for (int t4 = 0; t4 < 4; ++t4)
        acc[t4] = __builtin_amdgcn_mfma_f32_16x16x32_bf16(A[ks], B[t4][ks], acc[t4], 0, 0, 0);

    #pragma unroll
    for (int j = 0; j < 4; ++j) {
      const int eo = e0 + 16*m + 4*lg + j;
      const bool ok = (eo < nE);
      const int u = ok ? U[eo] : 0;
      #pragma unroll
      for (int t4 = 0; t4 < 4; ++t4) {
        const float other = __shfl_xor(acc[t4][j], 1);   // partner column
        if (ok && ((lr & 1) == (t4 >> 1))) {
          const int col0 = 64*ng + 16*t4 + (lr & ~1);
          const float lo = (lr & 1) ? other : acc[t4][j];
          const float hi = (lr & 1) ? acc[t4][j] : other;
          const unsigned int packed = ((unsigned int)f2bf(hi) << 16) | f2bf(lo);
          pk_atomic_add_bf16(&tempb[(size_t)u * NMC + col0], packed);
        }
      }
    }
  }
  // drain inline-asm atomics before wave exit (compiler doesn't track them)
  asm volatile("s_waitcnt vmcnt(0)" ::: "memory");
}

// ---------------------------------------------------------------------------
// k_gn: in-place per-row GroupNorm + ReLU on bf16 buffer (mid-layer norm).
// ---------------------------------------------------------------------------
__global__ __launch_bounds__(256) void k_gn(
    __hip_bfloat16* __restrict__ X, const float* __restrict__ gw,
    const float* __restrict__ gb)
{
  const int lane = threadIdx.x & 63;
  int n0 = (blockIdx.x * blockDim.x + threadIdx.x) >> 6;
  const int nWv = (gridDim.x * blockDim.x) >> 6;
  const float c0 = gw[2*lane], c1 = gw[2*lane+1];
  const float d0 = gb[2*lane], d1 = gb[2*lane+1];
  for (int n = n0; n < NN; n += nWv) {
    const size_t base = (size_t)n * NMC + 2*lane;
    const unsigned int xv = *(const unsigned int*)&X[base];
    const float x0 = bf2f((unsigned short)(xv & 0xffff));
    const float x1 = bf2f((unsigned short)(xv >> 16));
    float s  = x0 + x1;
    float s2 = x0*x0 + x1*x1;
    #pragma unroll
    for (int off = 32; off >= 1; off >>= 1) {
      s  += __shfl_xor(s, off);
      s2 += __shfl_xor(s2, off);
    }
    const float mu = s * (1.f/128.f);
    const float rs = rsqrtf(s2*(1.f/128.f) - mu*mu + 1e-5f);
    const float y0 = fmaxf((x0 - mu)*rs*c0 + d0, 0.f);
    const float y1 = fmaxf((x1 - mu)*rs*c1 + d1, 0.f);
    const unsigned int packed = ((unsigned int)f2bf(y1) << 16) | f2bf(y0);
    *(unsigned int*)&X[base] = packed;
  }
}

// ---------------------------------------------------------------------------
// k_combine: y = relu(fi + fs); featb = bf16(y); res = y.
// fi in res (f32), fs in outf (f32).
// ---------------------------------------------------------------------------
__global__ __launch_bounds__(256) void k_combine(
    const float* __restrict__ fs, float* __restrict__ res,
    __hip_bfloat16* __restrict__ featb)
{
  int64_t i = (int64_t)blockIdx.x * blockDim.x + threadIdx.x;
  const int64_t total = (int64_t)NN * 64;
  const int64_t stride = (int64_t)gridDim.x * blockDim.x;
  for (; i < total; i += stride) {
    const size_t base = (size_t)i * 2;
    const float2 a = *(const float2*)&res[base];
    const float2 b = *(const float2*)&fs[base];
    const float y0 = fmaxf(a.x + b.x, 0.f);
    const float y1 = fmaxf(a.y + b.y, 0.f);
    *(float2*)&res[base] = make_float2(y0, y1);
    const unsigned int packed = ((unsigned int)f2bf(y1) << 16) | f2bf(y0);
    *(unsigned int*)&featb[base] = packed;
  }
}

// ---------------------------------------------------------------------------
extern "C" void kernel_launch(void* const* d_in, const int* in_sizes, int n_in,
                              void* d_out, int out_size, void* d_ws, size_t ws_size,
                              hipStream_t stream)
{
  const float* ctrs     = (const float*)d_in[0];
  const float* feats    = (const float*)d_in[1];
  const int*   pre_u    = (const int*)d_in[2];
  const int*   pre_v    = (const int*)d_in[3];
  const int*   suc_u    = (const int*)d_in[4];
  const int*   suc_v    = (const int*)d_in[5];
  const int*   left_u   = (const int*)d_in[6];
  const int*   left_v   = (const int*)d_in[7];
  const int*   right_u  = (const int*)d_in[8];
  const int*   right_v  = (const int*)d_in[9];
  const float* in1_w    = (const float*)d_in[10];
  const float* in1_b    = (const float*)d_in[11];
  const float* in2_w    = (const float*)d_in[12];
  const float* in_gn_w  = (const float*)d_in[13];
  const float* in_gn_b  = (const float*)d_in[14];
  const float* seg1_w   = (const float*)d_in[15];
  const float* seg1_b   = (const float*)d_in[16];
  const float* seg2_w   = (const float*)d_in[17];
  const float* seg_gn_w = (const float*)d_in[18];
  const float* seg_gn_b = (const float*)d_in[19];
  const float* ctr_w    = (const float*)d_in[20];
  const float* pre_w    = (const float*)d_in[21];
  const float* suc_w    = (const float*)d_in[22];
  const float* left_w   = (const float*)d_in[23];
  const float* right_w  = (const float*)d_in[24];
  const float* norm_w   = (const float*)d_in[25];
  const float* norm_b   = (const float*)d_in[26];
  const float* ctr2_w   = (const float*)d_in[27];
  const float* ctr2_gn_w= (const float*)d_in[28];
  const float* ctr2_gn_b= (const float*)d_in[29];

  float* outf = (float*)d_out;                           // final f32 output
  __hip_bfloat16* tempb = (__hip_bfloat16*)d_ws;         // [N,128] bf16 accum
  __hip_bfloat16* featb = tempb + (size_t)NN * NMC;      // [N,128] bf16 features
  float* res = (float*)(featb + (size_t)NN * NMC);       // [N,128] f32 residual

  // ---- stems ----
  // fi: h1b(tempb) -> GEMM+GN -> res(f32)
  k_stem1b<<<2048, 256, 0, stream>>>(ctrs, in1_w, in1_b, tempb);
  k_dense<1><<<625, 256, 0, stream>>>(tempb, in2_w, nullptr, res, in_gn_w, in_gn_b, nullptr, 0);
  // fs: h1b(tempb) -> GEMM+GN -> outf(f32 scratch)
  k_stem1b<<<2048, 256, 0, stream>>>(feats, seg1_w, seg1_b, tempb);
  k_dense<1><<<625, 256, 0, stream>>>(tempb, seg2_w, nullptr, outf, seg_gn_w, seg_gn_b, nullptr, 0);
  // feat = relu(fi+fs) -> featb(bf16), res(f32)
  k_combine<<<2048, 256, 0, stream>>>(outf, res, featb);

  // ---- fusion layers ----
  for (int i = 0; i < LLAYERS; ++i) {
    const size_t wb = (size_t)i * NMC * NMC;
    // tempb = featb @ ctr_w[i].T   (bf16 store)
    k_dense<0><<<625, 256, 0, stream>>>(featb, ctr_w + wb, tempb, nullptr, nullptr, nullptr, nullptr, 0);
    // 14 edge-set scatter-GEMMs, packed bf16 atomics
    dim3 eg(256, 14);
    k_edge<<<eg, 256, 0, stream>>>(featb, tempb,
        pre_u, pre_v, suc_u, suc_v, left_u, left_v, right_u, right_v,
        pre_w, suc_w, left_w, right_w, i);
    // tempb = relu(GN(tempb)) in place
    k_gn<<<1024, 256, 0, stream>>>(tempb, norm_w + i*NMC, norm_b + i*NMC);
    // featb/res = relu(GN(tempb @ ctr2ᵀ) + res); last layer also writes f32 out
    k_dense<3><<<625, 256, 0, stream>>>(tempb, ctr2_w + wb, featb, outf,
        ctr2_gn_w + i*NMC, ctr2_gn_b + i*NMC, res, (i == LLAYERS-1) ? 1 : 0);
  }
}

// Round 4
// 2315.584 us; speedup vs baseline: 6.5641x; 1.2089x over previous
//
#include <hip/hip_runtime.h>
#include <hip/hip_bf16.h>

#define NN 100000
#define NMC 128
#define SS 6
#define EE 100000
#define ELR 30000
#define LLAYERS 4
#define TOT_E (12*EE + 2*ELR)          // 1,260,000
#define SCB 2048                        // elems per scan block
#define NSCB 49                         // ceil(NN/SCB)

typedef short s16x8 __attribute__((ext_vector_type(8)));
typedef float f32x4 __attribute__((ext_vector_type(4)));

__device__ inline unsigned short f2bf(float f) {
  __bf16 h = (__bf16)f;
  return __builtin_bit_cast(unsigned short, h);
}
__device__ inline float bf2f(unsigned short u) {
  unsigned int b = ((unsigned int)u) << 16;
  return __builtin_bit_cast(float, b);
}
__device__ inline s16x8 cvt8(float4 a, float4 b) {
  s16x8 r;
  r[0]=(short)f2bf(a.x); r[1]=(short)f2bf(a.y); r[2]=(short)f2bf(a.z); r[3]=(short)f2bf(a.w);
  r[4]=(short)f2bf(b.x); r[5]=(short)f2bf(b.y); r[6]=(short)f2bf(b.z); r[7]=(short)f2bf(b.w);
  return r;
}
// XOR-swizzled LDS addressing for a [32][128] f32 tile: 16B-block index XORed
// with (row&7) -> A-frag ds_read_b128 lands on 8 distinct banks-groups (2-way, free).
__device__ inline int swz(int row, int wordcol) {
  return row * 128 + ((((wordcol >> 2) ^ (row & 7)) << 2) | (wordcol & 3));
}

// ---------------------------------------------------------------------------
// Weight pool: all 66 [128][128] matrices converted f32 -> bf16 once per call.
// idx: 0 in2, 1 seg2, 2..5 ctr, 6..29 pre, 30..53 suc, 54..57 left,
//      58..61 right, 62..65 ctr2
// ---------------------------------------------------------------------------
__global__ __launch_bounds__(256) void k_wconv(
    const float* __restrict__ in2, const float* __restrict__ seg2,
    const float* __restrict__ ctr, const float* __restrict__ pre,
    const float* __restrict__ suc, const float* __restrict__ lw,
    const float* __restrict__ rw, const float* __restrict__ ctr2,
    __hip_bfloat16* __restrict__ Wb)
{
  const int total = 66 * NMC * NMC;
  for (int i = blockIdx.x * blockDim.x + threadIdx.x; i < total;
       i += gridDim.x * blockDim.x) {
    const int m = i >> 14, within = i & 16383;
    const float* src; int rel;
    if      (m == 0) { src = in2;  rel = 0; }
    else if (m == 1) { src = seg2; rel = 0; }
    else if (m < 6)  { src = ctr;  rel = m - 2; }
    else if (m < 30) { src = pre;  rel = m - 6; }
    else if (m < 54) { src = suc;  rel = m - 30; }
    else if (m < 58) { src = lw;   rel = m - 54; }
    else if (m < 62) { src = rw;   rel = m - 58; }
    else             { src = ctr2; rel = m - 62; }
    Wb[i] = __hip_bfloat16(bf2f(f2bf(src[rel * 16384 + within])));
  }
}

// ---------------------------------------------------------------------------
// CSR build: histogram -> block scan -> block-total scan -> add -> scatter.
// After k_scatter, ofs[s][u] holds the END offset of node u's edge list
// (set-local); start = (u==0) ? 0 : ofs[s][u-1].
// ---------------------------------------------------------------------------
__device__ inline void edge_decode(int idx, int& s, int& e) {
  if (idx < 12 * EE) { s = idx / EE; e = idx - s * EE; }
  else { int r = idx - 12 * EE; s = 12 + r / ELR; e = r - (s - 12) * ELR; }
}
__device__ inline int edge_u(int s, int e,
    const int* pu, const int* su, const int* lu, const int* ru) {
  if (s < 6)  return pu[s * EE + e];
  if (s < 12) return su[(s - 6) * EE + e];
  if (s == 12) return lu[e];
  return ru[e];
}
__device__ inline int edge_v(int s, int e,
    const int* pv, const int* sv, const int* lv, const int* rv) {
  if (s < 6)  return pv[s * EE + e];
  if (s < 12) return sv[(s - 6) * EE + e];
  if (s == 12) return lv[e];
  return rv[e];
}
__device__ inline int set_base(int s) {
  return (s < 12) ? s * EE : 12 * EE + (s - 12) * ELR;
}

__global__ __launch_bounds__(256) void k_hist(
    const int* __restrict__ pu, const int* __restrict__ su,
    const int* __restrict__ lu, const int* __restrict__ ru,
    int* __restrict__ cnt)
{
  for (int i = blockIdx.x * blockDim.x + threadIdx.x; i < TOT_E;
       i += gridDim.x * blockDim.x) {
    int s, e; edge_decode(i, s, e);
    atomicAdd(&cnt[s * NN + edge_u(s, e, pu, su, lu, ru)], 1);
  }
}

__global__ __launch_bounds__(256) void k_scan1(
    const int* __restrict__ cnt, int* __restrict__ ofs, int* __restrict__ btot)
{
  const int s = blockIdx.x / NSCB, b = blockIdx.x % NSCB;
  const int base = s * NN + b * SCB;
  const int lim = min(SCB, NN - b * SCB);   // elems in this chunk
  const int t = threadIdx.x;
  int loc[8]; int sum = 0;
  #pragma unroll
  for (int j = 0; j < 8; ++j) {
    const int idx = t * 8 + j;
    const int v = (idx < lim) ? cnt[base + idx] : 0;
    loc[j] = sum; sum += v;
  }
  __shared__ int sh[256];
  sh[t] = sum;
  __syncthreads();
  for (int off = 1; off < 256; off <<= 1) {
    const int v = (t >= off) ? sh[t - off] : 0;
    __syncthreads();
    sh[t] += v;
    __syncthreads();
  }
  const int excl = (t == 0) ? 0 : sh[t - 1];
  #pragma unroll
  for (int j = 0; j < 8; ++j) {
    const int idx = t * 8 + j;
    if (idx < lim) ofs[base + idx] = loc[j] + excl;
  }
  if (t == 255) btot[s * 64 + b] = sh[255];
}

__global__ __launch_bounds__(64) void k_scan2(int* __restrict__ btot)
{
  if (threadIdx.x != 0) return;
  const int s = blockIdx.x;
  int run = 0;
  for (int b = 0; b < NSCB; ++b) {
    const int tmp = btot[s * 64 + b];
    btot[s * 64 + b] = run;
    run += tmp;
  }
}

__global__ __launch_bounds__(256) void k_scan3(
    int* __restrict__ ofs, const int* __restrict__ btot)
{
  const int total = 14 * NN;
  for (int i = blockIdx.x * blockDim.x + threadIdx.x; i < total;
       i += gridDim.x * blockDim.x) {
    const int s = i / NN, u = i - s * NN;
    ofs[i] += btot[s * 64 + u / SCB];
  }
}

__global__ __launch_bounds__(256) void k_scatter(
    const int* __restrict__ pu, const int* __restrict__ su,
    const int* __restrict__ lu, const int* __restrict__ ru,
    const int* __restrict__ pv, const int* __restrict__ sv,
    const int* __restrict__ lv, const int* __restrict__ rv,
    int* __restrict__ ofs, int* __restrict__ vS)
{
  for (int i = blockIdx.x * blockDim.x + threadIdx.x; i < TOT_E;
       i += gridDim.x * blockDim.x) {
    int s, e; edge_decode(i, s, e);
    const int u = edge_u(s, e, pu, su, lu, ru);
    const int v = edge_v(s, e, pv, sv, lv, rv);
    const int pos = atomicAdd(&ofs[s * NN + u], 1);
    vS[set_base(s) + pos] = v;
  }
}

// ---------------------------------------------------------------------------
// k_stem1b: outb[n][o] = relu(w1[o][:2] . x[n][:2] + b1[o]), bf16 out.
// ---------------------------------------------------------------------------
__global__ __launch_bounds__(256) void k_stem1b(
    const float* __restrict__ x2, const float* __restrict__ w1,
    const float* __restrict__ b1, __hip_bfloat16* __restrict__ outb)
{
  int64_t i = (int64_t)blockIdx.x * blockDim.x + threadIdx.x;
  const int64_t total = (int64_t)NN * 64;
  const int64_t stride = (int64_t)gridDim.x * blockDim.x;
  for (; i < total; i += stride) {
    const int n = (int)(i >> 6);
    const int o = (int)(i & 63) * 2;
    const float2 xv = ((const float2*)x2)[n];
    const float v0 = fmaxf(w1[2*o]   * xv.x + w1[2*o+1] * xv.y + b1[o],   0.f);
    const float v1 = fmaxf(w1[2*o+2] * xv.x + w1[2*o+3] * xv.y + b1[o+1], 0.f);
    const unsigned int packed = ((unsigned int)f2bf(v1) << 16) | f2bf(v0);
    *(unsigned int*)&outb[(size_t)n * NMC + o] = packed;
  }
}

// ---------------------------------------------------------------------------
// k_dense<EPI>: Out = Xb @ Wb.T (bf16 A and B, f32 accum), N=100000 rows.
//   EPI=1: GN -> packed bf16 to outb (in-place on Xb is safe)
//   EPI=3: y = relu(GN(acc) + resb) -> outb; if wout, also f32 to outf
// Block 4 waves, tile 32x128. MFMA 16x16x32 layouts as established.
// ---------------------------------------------------------------------------
template<int EPI>
__global__ __launch_bounds__(256) void k_dense(
    const __hip_bfloat16* __restrict__ Xb, const __hip_bfloat16* __restrict__ Wbs,
    __hip_bfloat16* __restrict__ outb, float* __restrict__ outf,
    const float* __restrict__ gw, const float* __restrict__ gb,
    const __hip_bfloat16* __restrict__ resb, int wout)
{
  __shared__ float cl[32 * 129];
  const int lane = threadIdx.x & 63;
  const int w = threadIdx.x >> 6;
  const int m = w & 1, ng = w >> 1;
  const int lr = lane & 15, lg = lane >> 4;

  s16x8 B[4][4];
  #pragma unroll
  for (int t4 = 0; t4 < 4; ++t4)
    #pragma unroll
    for (int ks = 0; ks < 4; ++ks)
      B[t4][ks] = *(const s16x8*)&Wbs[(64*ng + 16*t4 + lr) * NMC + 32*ks + 8*lg];

  const float gwc0 = gw[2*lane], gwc1 = gw[2*lane+1];
  const float gbc0 = gb[2*lane], gbc1 = gb[2*lane+1];

  const int nTiles = NN / 32;
  for (int tile = blockIdx.x; tile < nTiles; tile += gridDim.x) {
    const int row = tile*32 + 16*m + lr;
    s16x8 A[4];
    #pragma unroll
    for (int ks = 0; ks < 4; ++ks)
      A[ks] = *(const s16x8*)&Xb[(size_t)row * NMC + 32*ks + 8*lg];

    f32x4 acc[4] = {};
    #pragma unroll
    for (int ks = 0; ks < 4; ++ks)
      #pragma unroll
      for (int t4 = 0; t4 < 4; ++t4)
        acc[t4] = __builtin_amdgcn_mfma_f32_16x16x32_bf16(A[ks], B[t4][ks], acc[t4], 0, 0, 0);

    #pragma unroll
    for (int j = 0; j < 4; ++j) {
      const int r = 16*m + 4*lg + j;
      #pragma unroll
      for (int t4 = 0; t4 < 4; ++t4)
        cl[r * 129 + 64*ng + 16*t4 + lr] = acc[t4][j];
    }
    __syncthreads();
    #pragma unroll
    for (int rr = 0; rr < 8; ++rr) {
      const int r = rr*4 + w;
      const float x0 = cl[r*129 + 2*lane];
      const float x1 = cl[r*129 + 2*lane + 1];
      float s  = x0 + x1;
      float s2 = x0*x0 + x1*x1;
      #pragma unroll
      for (int off = 32; off >= 1; off >>= 1) {
        s  += __shfl_xor(s, off);
        s2 += __shfl_xor(s2, off);
      }
      const float mu = s * (1.f/128.f);
      const float rs = rsqrtf(s2*(1.f/128.f) - mu*mu + 1e-5f);
      float y0 = (x0 - mu)*rs*gwc0 + gbc0;
      float y1 = (x1 - mu)*rs*gwc1 + gbc1;
      const size_t base = (size_t)(tile*32 + r) * NMC + 2*lane;
      if (EPI == 3) {
        const unsigned int rp = *(const unsigned int*)&resb[base];
        y0 = fmaxf(y0 + bf2f((unsigned short)(rp & 0xffff)), 0.f);
        y1 = fmaxf(y1 + bf2f((unsigned short)(rp >> 16)), 0.f);
      }
      const unsigned int packed = ((unsigned int)f2bf(y1) << 16) | f2bf(y0);
      *(unsigned int*)&outb[base] = packed;
      if (EPI == 3 && wout) *(float2*)&outf[base] = make_float2(y0, y1);
    }
    __syncthreads();
  }
}

// ---------------------------------------------------------------------------
// k_layer: the whole message-passing step for one layer, zero atomics.
// Block = 32 node rows. For each set s in [0,15):
//   s<14:  agg[row] = sum over CSR_s edges of featb[v]   (f32 registers)
//   s==14: agg[row] = featb[row]                          (ctr identity)
//   stage agg in swizzled LDS -> 16 MFMA/wave with Wb_s streamed from L2,
//   accumulating one C tile across all 15 sets.
// Epilogue: GroupNorm + ReLU fused (rows complete) -> tempb (bf16).
// ---------------------------------------------------------------------------
__global__ __launch_bounds__(256) void k_layer(
    const __hip_bfloat16* __restrict__ featb, __hip_bfloat16* __restrict__ tempb,
    const __hip_bfloat16* __restrict__ Wb, const int* __restrict__ ofs,
    const int* __restrict__ vS, const float* __restrict__ gw,
    const float* __restrict__ gb, int layer)
{
  __shared__ float cl[32 * 128];
  const int t = threadIdx.x;
  const int lane = t & 63, w = t >> 6;
  const int m = w & 1, ng = w >> 1;
  const int lr = lane & 15, lg = lane >> 4;
  const int row = t >> 3;            // 0..31 (agg phase)
  const int ch  = (t & 7) * 16;      // 16-channel chunk base
  const int tile = blockIdx.x;
  const int gu = tile * 32 + row;

  const float gwc0 = gw[2*lane], gwc1 = gw[2*lane+1];
  const float gbc0 = gb[2*lane], gbc1 = gb[2*lane+1];

  f32x4 acc[4] = {};
  for (int s = 0; s < 15; ++s) {
    // ---- aggregate into f32 regs ----
    float a[16];
    #pragma unroll
    for (int q = 0; q < 16; ++q) a[q] = 0.f;
    if (s == 14) {
      const s16x8* p = (const s16x8*)&featb[(size_t)gu * NMC + ch];
      const s16x8 x0 = p[0], x1 = p[1];
      #pragma unroll
      for (int q = 0; q < 8; ++q) {
        a[q]   = bf2f((unsigned short)x0[q]);
        a[8+q] = bf2f((unsigned short)x1[q]);
      }
    } else {
      const int st = (gu == 0) ? 0 : ofs[s * NN + gu - 1];
      const int en = ofs[s * NN + gu];
      const int base = set_base(s);
      for (int j = st; j < en; ++j) {
        const int vv = vS[base + j];
        const s16x8* p = (const s16x8*)&featb[(size_t)vv * NMC + ch];
        const s16x8 x0 = p[0], x1 = p[1];
        #pragma unroll
        for (int q = 0; q < 8; ++q) {
          a[q]   += bf2f((unsigned short)x0[q]);
          a[8+q] += bf2f((unsigned short)x1[q]);
        }
      }
    }
    // ---- stage in swizzled LDS ----
    #pragma unroll
    for (int q = 0; q < 4; ++q)
      *(float4*)&cl[swz(row, ch + 4*q)] = make_float4(a[4*q], a[4*q+1], a[4*q+2], a[4*q+3]);
    __syncthreads();
    // ---- MFMA with streamed B ----
    int wbidx;
    if      (s < 6)  wbidx = 6 + layer*6 + s;
    else if (s < 12) wbidx = 30 + layer*6 + (s - 6);
    else if (s == 12) wbidx = 54 + layer;
    else if (s == 13) wbidx = 58 + layer;
    else              wbidx = 2 + layer;
    const __hip_bfloat16* Wbs = Wb + (size_t)wbidx * NMC * NMC;
    #pragma unroll
    for (int ks = 0; ks < 4; ++ks) {
      const float4 a0 = *(const float4*)&cl[swz(16*m + lr, 32*ks + 8*lg)];
      const float4 a1 = *(const float4*)&cl[swz(16*m + lr, 32*ks + 8*lg + 4)];
      const s16x8 A = cvt8(a0, a1);
      #pragma unroll
      for (int t4 = 0; t4 < 4; ++t4) {
        const s16x8 B = *(const s16x8*)&Wbs[(64*ng + 16*t4 + lr) * NMC + 32*ks + 8*lg];
        acc[t4] = __builtin_amdgcn_mfma_f32_16x16x32_bf16(A, B, acc[t4], 0, 0, 0);
      }
    }
    __syncthreads();
  }

  // ---- fused GroupNorm + ReLU -> tempb ----
  #pragma unroll
  for (int j = 0; j < 4; ++j) {
    const int r = 16*m + 4*lg + j;
    #pragma unroll
    for (int t4 = 0; t4 < 4; ++t4)
      cl[swz(r, 64*ng + 16*t4 + lr)] = acc[t4][j];
  }
  __syncthreads();
  #pragma unroll
  for (int rr = 0; rr < 8; ++rr) {
    const int r = rr*4 + w;
    const float x0 = cl[swz(r, 2*lane)];
    const float x1 = cl[swz(r, 2*lane + 1)];
    float s  = x0 + x1;
    float s2 = x0*x0 + x1*x1;
    #pragma unroll
    for (int off = 32; off >= 1; off >>= 1) {
      s  += __shfl_xor(s, off);
      s2 += __shfl_xor(s2, off);
    }
    const float mu = s * (1.f/128.f);
    const float rs = rsqrtf(s2*(1.f/128.f) - mu*mu + 1e-5f);
    const float y0 = fmaxf((x0 - mu)*rs*gwc0 + gbc0, 0.f);
    const float y1 = fmaxf((x1 - mu)*rs*gwc1 + gbc1, 0.f);
    const unsigned int packed = ((unsigned int)f2bf(y1) << 16) | f2bf(y0);
    *(unsigned int*)&tempb[(size_t)(tile*32 + r) * NMC + 2*lane] = packed;
  }
}

// ---------------------------------------------------------------------------
// k_combine: featb = bf16(relu(fi + fs));  fi in tempb, fs in featb.
// ---------------------------------------------------------------------------
__global__ __launch_bounds__(256) void k_combine(
    const __hip_bfloat16* __restrict__ fib, __hip_bfloat16* __restrict__ featb)
{
  int64_t i = (int64_t)blockIdx.x * blockDim.x + threadIdx.x;
  const int64_t total = (int64_t)NN * 64;
  const int64_t stride = (int64_t)gridDim.x * blockDim.x;
  for (; i < total; i += stride) {
    const unsigned int ap = ((const unsigned int*)fib)[i];
    const unsigned int bp = ((const unsigned int*)featb)[i];
    const float y0 = fmaxf(bf2f((unsigned short)(ap & 0xffff)) + bf2f((unsigned short)(bp & 0xffff)), 0.f);
    const float y1 = fmaxf(bf2f((unsigned short)(ap >> 16))    + bf2f((unsigned short)(bp >> 16)), 0.f);
    ((unsigned int*)featb)[i] = ((unsigned int)f2bf(y1) << 16) | f2bf(y0);
  }
}

// ---------------------------------------------------------------------------
extern "C" void kernel_launch(void* const* d_in, const int* in_sizes, int n_in,
                              void* d_out, int out_size, void* d_ws, size_t ws_size,
                              hipStream_t stream)
{
  const float* ctrs     = (const float*)d_in[0];
  const float* feats    = (const float*)d_in[1];
  const int*   pre_u    = (const int*)d_in[2];
  const int*   pre_v    = (const int*)d_in[3];
  const int*   suc_u    = (const int*)d_in[4];
  const int*   suc_v    = (const int*)d_in[5];
  const int*   left_u   = (const int*)d_in[6];
  const int*   left_v   = (const int*)d_in[7];
  const int*   right_u  = (const int*)d_in[8];
  const int*   right_v  = (const int*)d_in[9];
  const float* in1_w    = (const float*)d_in[10];
  const float* in1_b    = (const float*)d_in[11];
  const float* in2_w    = (const float*)d_in[12];
  const float* in_gn_w  = (const float*)d_in[13];
  const float* in_gn_b  = (const float*)d_in[14];
  const float* seg1_w   = (const float*)d_in[15];
  const float* seg1_b   = (const float*)d_in[16];
  const float* seg2_w   = (const float*)d_in[17];
  const float* seg_gn_w = (const float*)d_in[18];
  const float* seg_gn_b = (const float*)d_in[19];
  const float* ctr_w    = (const float*)d_in[20];
  const float* pre_w    = (const float*)d_in[21];
  const float* suc_w    = (const float*)d_in[22];
  const float* left_w   = (const float*)d_in[23];
  const float* right_w  = (const float*)d_in[24];
  const float* norm_w   = (const float*)d_in[25];
  const float* norm_b   = (const float*)d_in[26];
  const float* ctr2_w   = (const float*)d_in[27];
  const float* ctr2_gn_w= (const float*)d_in[28];
  const float* ctr2_gn_b= (const float*)d_in[29];

  // workspace layout (all offsets 256B-aligned)
  char* ws = (char*)d_ws;
  __hip_bfloat16* tempb = (__hip_bfloat16*)(ws);                 // 25,600,000
  __hip_bfloat16* featb = (__hip_bfloat16*)(ws + 25600000);      // 25,600,000
  __hip_bfloat16* Wb    = (__hip_bfloat16*)(ws + 51200000);      //  2,162,688
  int* cnt  = (int*)(ws + 53362688);                             //  5,600,000
  int* ofs  = (int*)(ws + 58962688);                             //  5,600,000
  int* vS   = (int*)(ws + 64562688);                             //  5,040,000
  int* btot = (int*)(ws + 69602688);                             //      3,584
  float* outf = (float*)d_out;

  // ---- weight pool conversion + CSR build (once per call) ----
  k_wconv<<<2048, 256, 0, stream>>>(in2_w, seg2_w, ctr_w, pre_w, suc_w,
                                    left_w, right_w, ctr2_w, Wb);
  hipMemsetAsync(cnt, 0, (size_t)14 * NN * 4, stream);
  k_hist<<<1232, 256, 0, stream>>>(pre_u, suc_u, left_u, right_u, cnt);
  k_scan1<<<14 * NSCB, 256, 0, stream>>>(cnt, ofs, btot);
  k_scan2<<<14, 64, 0, stream>>>(btot);
  k_scan3<<<2048, 256, 0, stream>>>(ofs, btot);
  k_scatter<<<1232, 256, 0, stream>>>(pre_u, suc_u, left_u, right_u,
                                      pre_v, suc_v, left_v, right_v, ofs, vS);

  // ---- stems ----
  k_stem1b<<<2048, 256, 0, stream>>>(ctrs, in1_w, in1_b, tempb);
  k_dense<1><<<625, 256, 0, stream>>>(tempb, Wb + 0*16384, tempb, nullptr,
                                      in_gn_w, in_gn_b, nullptr, 0);
  k_stem1b<<<2048, 256, 0, stream>>>(feats, seg1_w, seg1_b, featb);
  k_dense<1><<<625, 256, 0, stream>>>(featb, Wb + 1*16384, featb, nullptr,
                                      seg_gn_w, seg_gn_b, nullptr, 0);
  k_combine<<<2048, 256, 0, stream>>>(tempb, featb);

  // ---- fusion layers: 2 dispatches each ----
  for (int i = 0; i < LLAYERS; ++i) {
    k_layer<<<NN/32, 256, 0, stream>>>(featb, tempb, Wb, ofs, vS,
                                       norm_w + i*NMC, norm_b + i*NMC, i);
    k_dense<3><<<625, 256, 0, stream>>>(tempb, Wb + (size_t)(62+i)*16384,
                                        featb, outf,
                                        ctr2_gn_w + i*NMC, ctr2_gn_b + i*NMC,
                                        featb, (i == LLAYERS-1) ? 1 : 0);
  }
}

// Round 5
// 1794.133 us; speedup vs baseline: 8.4719x; 1.2906x over previous
//
#include <hip/hip_runtime.h>
#include <hip/hip_bf16.h>

#define NN 100000
#define NMC 128
#define SS 6
#define EE 100000
#define ELR 30000
#define LLAYERS 4
#define TOT_E (12*EE + 2*ELR)          // 1,260,000
#define SCB 2048                        // elems per scan block
#define NSCB 49                         // ceil(NN/SCB)

typedef short s16x8 __attribute__((ext_vector_type(8)));
typedef float f32x4 __attribute__((ext_vector_type(4)));

__device__ inline unsigned short f2bf(float f) {
  __bf16 h = (__bf16)f;
  return __builtin_bit_cast(unsigned short, h);
}
__device__ inline float bf2f(unsigned short u) {
  unsigned int b = ((unsigned int)u) << 16;
  return __builtin_bit_cast(float, b);
}
__device__ inline s16x8 cvt8(float4 a, float4 b) {
  s16x8 r;
  r[0]=(short)f2bf(a.x); r[1]=(short)f2bf(a.y); r[2]=(short)f2bf(a.z); r[3]=(short)f2bf(a.w);
  r[4]=(short)f2bf(b.x); r[5]=(short)f2bf(b.y); r[6]=(short)f2bf(b.z); r[7]=(short)f2bf(b.w);
  return r;
}

// ---------------------------------------------------------------------------
// Weight pool: all 66 [128][128] matrices converted f32 -> bf16 once per call.
// idx: 0 in2, 1 seg2, 2..5 ctr, 6..29 pre, 30..53 suc, 54..57 left,
//      58..61 right, 62..65 ctr2
// ---------------------------------------------------------------------------
__global__ __launch_bounds__(256) void k_wconv(
    const float* __restrict__ in2, const float* __restrict__ seg2,
    const float* __restrict__ ctr, const float* __restrict__ pre,
    const float* __restrict__ suc, const float* __restrict__ lw,
    const float* __restrict__ rw, const float* __restrict__ ctr2,
    __hip_bfloat16* __restrict__ Wb)
{
  const int total = 66 * NMC * NMC;
  for (int i = blockIdx.x * blockDim.x + threadIdx.x; i < total;
       i += gridDim.x * blockDim.x) {
    const int m = i >> 14, within = i & 16383;
    const float* src; int rel;
    if      (m == 0) { src = in2;  rel = 0; }
    else if (m == 1) { src = seg2; rel = 0; }
    else if (m < 6)  { src = ctr;  rel = m - 2; }
    else if (m < 30) { src = pre;  rel = m - 6; }
    else if (m < 54) { src = suc;  rel = m - 30; }
    else if (m < 58) { src = lw;   rel = m - 54; }
    else if (m < 62) { src = rw;   rel = m - 58; }
    else             { src = ctr2; rel = m - 62; }
    Wb[i] = __hip_bfloat16(bf2f(f2bf(src[rel * 16384 + within])));
  }
}

// ---------------------------------------------------------------------------
// CSR build: histogram -> block scan -> block-total scan -> add -> scatter.
// After k_scatter, ofs[s][u] holds the END offset of node u's edge list
// (set-local); start = (u==0) ? 0 : ofs[s][u-1].
// ---------------------------------------------------------------------------
__device__ inline void edge_decode(int idx, int& s, int& e) {
  if (idx < 12 * EE) { s = idx / EE; e = idx - s * EE; }
  else { int r = idx - 12 * EE; s = 12 + r / ELR; e = r - (s - 12) * ELR; }
}
__device__ inline int edge_u(int s, int e,
    const int* pu, const int* su, const int* lu, const int* ru) {
  if (s < 6)  return pu[s * EE + e];
  if (s < 12) return su[(s - 6) * EE + e];
  if (s == 12) return lu[e];
  return ru[e];
}
__device__ inline int edge_v(int s, int e,
    const int* pv, const int* sv, const int* lv, const int* rv) {
  if (s < 6)  return pv[s * EE + e];
  if (s < 12) return sv[(s - 6) * EE + e];
  if (s == 12) return lv[e];
  return rv[e];
}
__device__ inline int set_base(int s) {
  return (s < 12) ? s * EE : 12 * EE + (s - 12) * ELR;
}

__global__ __launch_bounds__(256) void k_hist(
    const int* __restrict__ pu, const int* __restrict__ su,
    const int* __restrict__ lu, const int* __restrict__ ru,
    int* __restrict__ cnt)
{
  for (int i = blockIdx.x * blockDim.x + threadIdx.x; i < TOT_E;
       i += gridDim.x * blockDim.x) {
    int s, e; edge_decode(i, s, e);
    atomicAdd(&cnt[s * NN + edge_u(s, e, pu, su, lu, ru)], 1);
  }
}

__global__ __launch_bounds__(256) void k_scan1(
    const int* __restrict__ cnt, int* __restrict__ ofs, int* __restrict__ btot)
{
  const int s = blockIdx.x / NSCB, b = blockIdx.x % NSCB;
  const int base = s * NN + b * SCB;
  const int lim = min(SCB, NN - b * SCB);   // elems in this chunk
  const int t = threadIdx.x;
  int loc[8]; int sum = 0;
  #pragma unroll
  for (int j = 0; j < 8; ++j) {
    const int idx = t * 8 + j;
    const int v = (idx < lim) ? cnt[base + idx] : 0;
    loc[j] = sum; sum += v;
  }
  __shared__ int sh[256];
  sh[t] = sum;
  __syncthreads();
  for (int off = 1; off < 256; off <<= 1) {
    const int v = (t >= off) ? sh[t - off] : 0;
    __syncthreads();
    sh[t] += v;
    __syncthreads();
  }
  const int excl = (t == 0) ? 0 : sh[t - 1];
  #pragma unroll
  for (int j = 0; j < 8; ++j) {
    const int idx = t * 8 + j;
    if (idx < lim) ofs[base + idx] = loc[j] + excl;
  }
  if (t == 255) btot[s * 64 + b] = sh[255];
}

__global__ __launch_bounds__(64) void k_scan2(int* __restrict__ btot)
{
  if (threadIdx.x != 0) return;
  const int s = blockIdx.x;
  int run = 0;
  for (int b = 0; b < NSCB; ++b) {
    const int tmp = btot[s * 64 + b];
    btot[s * 64 + b] = run;
    run += tmp;
  }
}

__global__ __launch_bounds__(256) void k_scan3(
    int* __restrict__ ofs, const int* __restrict__ btot)
{
  const int total = 14 * NN;
  for (int i = blockIdx.x * blockDim.x + threadIdx.x; i < total;
       i += gridDim.x * blockDim.x) {
    const int s = i / NN, u = i - s * NN;
    ofs[i] += btot[s * 64 + u / SCB];
  }
}

__global__ __launch_bounds__(256) void k_scatter(
    const int* __restrict__ pu, const int* __restrict__ su,
    const int* __restrict__ lu, const int* __restrict__ ru,
    const int* __restrict__ pv, const int* __restrict__ sv,
    const int* __restrict__ lv, const int* __restrict__ rv,
    int* __restrict__ ofs, int* __restrict__ vS)
{
  for (int i = blockIdx.x * blockDim.x + threadIdx.x; i < TOT_E;
       i += gridDim.x * blockDim.x) {
    int s, e; edge_decode(i, s, e);
    const int u = edge_u(s, e, pu, su, lu, ru);
    const int v = edge_v(s, e, pv, sv, lv, rv);
    const int pos = atomicAdd(&ofs[s * NN + u], 1);
    vS[set_base(s) + pos] = v;
  }
}

// ---------------------------------------------------------------------------
// k_stem1b: outb[n][o] = relu(w1[o][:2] . x[n][:2] + b1[o]), bf16 out.
// ---------------------------------------------------------------------------
__global__ __launch_bounds__(256) void k_stem1b(
    const float* __restrict__ x2, const float* __restrict__ w1,
    const float* __restrict__ b1, __hip_bfloat16* __restrict__ outb)
{
  int64_t i = (int64_t)blockIdx.x * blockDim.x + threadIdx.x;
  const int64_t total = (int64_t)NN * 64;
  const int64_t stride = (int64_t)gridDim.x * blockDim.x;
  for (; i < total; i += stride) {
    const int n = (int)(i >> 6);
    const int o = (int)(i & 63) * 2;
    const float2 xv = ((const float2*)x2)[n];
    const float v0 = fmaxf(w1[2*o]   * xv.x + w1[2*o+1] * xv.y + b1[o],   0.f);
    const float v1 = fmaxf(w1[2*o+2] * xv.x + w1[2*o+3] * xv.y + b1[o+1], 0.f);
    const unsigned int packed = ((unsigned int)f2bf(v1) << 16) | f2bf(v0);
    *(unsigned int*)&outb[(size_t)n * NMC + o] = packed;
  }
}

// ---------------------------------------------------------------------------
// k_dense<EPI>: Out = Xb @ Wb.T (bf16 A and B, f32 accum), N=100000 rows.
//   EPI=1: GN -> packed bf16 to outb (in-place on Xb is safe)
//   EPI=3: y = relu(GN(acc) + resb) -> outb; if wout, also f32 to outf
// ---------------------------------------------------------------------------
template<int EPI>
__global__ __launch_bounds__(256) void k_dense(
    const __hip_bfloat16* __restrict__ Xb, const __hip_bfloat16* __restrict__ Wbs,
    __hip_bfloat16* __restrict__ outb, float* __restrict__ outf,
    const float* __restrict__ gw, const float* __restrict__ gb,
    const __hip_bfloat16* __restrict__ resb, int wout)
{
  __shared__ float cl[32 * 129];
  const int lane = threadIdx.x & 63;
  const int w = threadIdx.x >> 6;
  const int m = w & 1, ng = w >> 1;
  const int lr = lane & 15, lg = lane >> 4;

  s16x8 B[4][4];
  #pragma unroll
  for (int t4 = 0; t4 < 4; ++t4)
    #pragma unroll
    for (int ks = 0; ks < 4; ++ks)
      B[t4][ks] = *(const s16x8*)&Wbs[(64*ng + 16*t4 + lr) * NMC + 32*ks + 8*lg];

  const float gwc0 = gw[2*lane], gwc1 = gw[2*lane+1];
  const float gbc0 = gb[2*lane], gbc1 = gb[2*lane+1];

  const int nTiles = NN / 32;
  for (int tile = blockIdx.x; tile < nTiles; tile += gridDim.x) {
    const int row = tile*32 + 16*m + lr;
    s16x8 A[4];
    #pragma unroll
    for (int ks = 0; ks < 4; ++ks)
      A[ks] = *(const s16x8*)&Xb[(size_t)row * NMC + 32*ks + 8*lg];

    f32x4 acc[4] = {};
    #pragma unroll
    for (int ks = 0; ks < 4; ++ks)
      #pragma unroll
      for (int t4 = 0; t4 < 4; ++t4)
        acc[t4] = __builtin_amdgcn_mfma_f32_16x16x32_bf16(A[ks], B[t4][ks], acc[t4], 0, 0, 0);

    #pragma unroll
    for (int j = 0; j < 4; ++j) {
      const int r = 16*m + 4*lg + j;
      #pragma unroll
      for (int t4 = 0; t4 < 4; ++t4)
        cl[r * 129 + 64*ng + 16*t4 + lr] = acc[t4][j];
    }
    __syncthreads();
    #pragma unroll
    for (int rr = 0; rr < 8; ++rr) {
      const int r = rr*4 + w;
      const float x0 = cl[r*129 + 2*lane];
      const float x1 = cl[r*129 + 2*lane + 1];
      float s  = x0 + x1;
      float s2 = x0*x0 + x1*x1;
      #pragma unroll
      for (int off = 32; off >= 1; off >>= 1) {
        s  += __shfl_xor(s, off);
        s2 += __shfl_xor(s2, off);
      }
      const float mu = s * (1.f/128.f);
      const float rs = rsqrtf(s2*(1.f/128.f) - mu*mu + 1e-5f);
      float y0 = (x0 - mu)*rs*gwc0 + gbc0;
      float y1 = (x1 - mu)*rs*gwc1 + gbc1;
      const size_t base = (size_t)(tile*32 + r) * NMC + 2*lane;
      if (EPI == 3) {
        const unsigned int rp = *(const unsigned int*)&resb[base];
        y0 = fmaxf(y0 + bf2f((unsigned short)(rp & 0xffff)), 0.f);
        y1 = fmaxf(y1 + bf2f((unsigned short)(rp >> 16)), 0.f);
      }
      const unsigned int packed = ((unsigned int)f2bf(y1) << 16) | f2bf(y0);
      *(unsigned int*)&outb[base] = packed;
      if (EPI == 3 && wout) *(float2*)&outf[base] = make_float2(y0, y1);
    }
    __syncthreads();
  }
}

// ---------------------------------------------------------------------------
// k_layer: one layer's message passing; ZERO LDS, ZERO barriers.
// Each WAVE owns a private 32-row tile (2 m-blocks of 16 rows). Lane role:
// lr=lane&15 is the A-fragment row, lg=lane>>4 owns k-chunks 8*lg+32*ks.
// Per set: aggregate incident featb rows straight into A-fragment channel
// slots (f32), cvt to bf16 frags, stream B from the L2-hot weight pool,
// 64 MFMAs into persistent acc. Identity (ctr) set goes first and loads A
// directly as bf16. CSR offsets for set s+1 are prefetched during set s.
// Epilogue: GN+ReLU via intra-wave shfl (row r lives in lanes lg=r>>2).
// ---------------------------------------------------------------------------
__global__ __launch_bounds__(256) void k_layer(
    const __hip_bfloat16* __restrict__ featb, __hip_bfloat16* __restrict__ tempb,
    const __hip_bfloat16* __restrict__ Wb, const int* __restrict__ ofs,
    const int* __restrict__ vS, const float* __restrict__ gw,
    const float* __restrict__ gb, int layer)
{
  const int lane = threadIdx.x & 63;
  const int wv = threadIdx.x >> 6;
  const int tile = blockIdx.x * 4 + wv;
  if (tile >= NN/32) return;
  const int lr = lane & 15, lg = lane >> 4;
  const int r0 = tile * 32;
  const int gu0 = r0 + lr, gu1 = r0 + 16 + lr;

  f32x4 acc[2][8] = {};

  // ---- set 0: identity (ctr) — A direct from bf16 featb ----
  {
    s16x8 A0[4], A1[4];
    #pragma unroll
    for (int ks = 0; ks < 4; ++ks) {
      A0[ks] = *(const s16x8*)&featb[(size_t)gu0 * NMC + 32*ks + 8*lg];
      A1[ks] = *(const s16x8*)&featb[(size_t)gu1 * NMC + 32*ks + 8*lg];
    }
    const __hip_bfloat16* Wbs = Wb + (size_t)(2 + layer) * NMC * NMC;
    #pragma unroll
    for (int ks = 0; ks < 4; ++ks)
      #pragma unroll
      for (int t4 = 0; t4 < 8; ++t4) {
        const s16x8 Bf = *(const s16x8*)&Wbs[(16*t4 + lr) * NMC + 32*ks + 8*lg];
        acc[0][t4] = __builtin_amdgcn_mfma_f32_16x16x32_bf16(A0[ks], Bf, acc[0][t4], 0, 0, 0);
        acc[1][t4] = __builtin_amdgcn_mfma_f32_16x16x32_bf16(A1[ks], Bf, acc[1][t4], 0, 0, 0);
      }
  }

  // CSR offsets for set 0 (gu1 >= 16, never node 0)
  int cst0 = (gu0 == 0) ? 0 : ofs[gu0 - 1];
  int cen0 = ofs[gu0];
  int cst1 = ofs[gu1 - 1];
  int cen1 = ofs[gu1];

  for (int p = 1; p <= 14; ++p) {
    const int s = p - 1;
    // depth-1 prefetch of next set's offsets
    int nst0 = 0, nen0 = 0, nst1 = 0, nen1 = 0;
    if (p < 14) {
      const int b = (s + 1) * NN;
      nst0 = (gu0 == 0) ? 0 : ofs[b + gu0 - 1];
      nen0 = ofs[b + gu0];
      nst1 = ofs[b + gu1 - 1];
      nen1 = ofs[b + gu1];
    }
    const int base = set_base(s);

    s16x8 A0[4], A1[4];
    {
      float a[32];
      #pragma unroll
      for (int q = 0; q < 32; ++q) a[q] = 0.f;
      for (int j = cst0; j < cen0; ++j) {
        const int vv = vS[base + j];
        #pragma unroll
        for (int ks = 0; ks < 4; ++ks) {
          const s16x8 x = *(const s16x8*)&featb[(size_t)vv * NMC + 32*ks + 8*lg];
          #pragma unroll
          for (int q = 0; q < 8; ++q) a[8*ks + q] += bf2f((unsigned short)x[q]);
        }
      }
      #pragma unroll
      for (int ks = 0; ks < 4; ++ks) {
        s16x8 r;
        #pragma unroll
        for (int q = 0; q < 8; ++q) r[q] = (short)f2bf(a[8*ks + q]);
        A0[ks] = r;
      }
    }
    {
      float a[32];
      #pragma unroll
      for (int q = 0; q < 32; ++q) a[q] = 0.f;
      for (int j = cst1; j < cen1; ++j) {
        const int vv = vS[base + j];
        #pragma unroll
        for (int ks = 0; ks < 4; ++ks) {
          const s16x8 x = *(const s16x8*)&featb[(size_t)vv * NMC + 32*ks + 8*lg];
          #pragma unroll
          for (int q = 0; q < 8; ++q) a[8*ks + q] += bf2f((unsigned short)x[q]);
        }
      }
      #pragma unroll
      for (int ks = 0; ks < 4; ++ks) {
        s16x8 r;
        #pragma unroll
        for (int q = 0; q < 8; ++q) r[q] = (short)f2bf(a[8*ks + q]);
        A1[ks] = r;
      }
    }

    int wbidx;
    if      (s < 6)  wbidx = 6 + layer*6 + s;
    else if (s < 12) wbidx = 30 + layer*6 + (s - 6);
    else if (s == 12) wbidx = 54 + layer;
    else              wbidx = 58 + layer;
    const __hip_bfloat16* Wbs = Wb + (size_t)wbidx * NMC * NMC;
    #pragma unroll
    for (int ks = 0; ks < 4; ++ks)
      #pragma unroll
      for (int t4 = 0; t4 < 8; ++t4) {
        const s16x8 Bf = *(const s16x8*)&Wbs[(16*t4 + lr) * NMC + 32*ks + 8*lg];
        acc[0][t4] = __builtin_amdgcn_mfma_f32_16x16x32_bf16(A0[ks], Bf, acc[0][t4], 0, 0, 0);
        acc[1][t4] = __builtin_amdgcn_mfma_f32_16x16x32_bf16(A1[ks], Bf, acc[1][t4], 0, 0, 0);
      }
    cst0 = nst0; cen0 = nen0; cst1 = nst1; cen1 = nen1;
  }

  // ---- epilogue: GroupNorm + ReLU, intra-wave ----
  float gwc[8], gbc[8];
  #pragma unroll
  for (int t4 = 0; t4 < 8; ++t4) {
    gwc[t4] = gw[16*t4 + lr];
    gbc[t4] = gb[16*t4 + lr];
  }
  #pragma unroll
  for (int m = 0; m < 2; ++m) {
    #pragma unroll
    for (int j = 0; j < 4; ++j) {
      float sum = 0.f, sq = 0.f;
      #pragma unroll
      for (int t4 = 0; t4 < 8; ++t4) {
        const float v = acc[m][t4][j];
        sum += v; sq += v*v;
      }
      // reduce over the 16-lane lr dimension (lane bits 0..3)
      #pragma unroll
      for (int off = 1; off <= 8; off <<= 1) {
        sum += __shfl_xor(sum, off);
        sq  += __shfl_xor(sq,  off);
      }
      const float mu = sum * (1.f/128.f);
      const float rs = rsqrtf(sq*(1.f/128.f) - mu*mu + 1e-5f);
      float y[8];
      #pragma unroll
      for (int t4 = 0; t4 < 8; ++t4)
        y[t4] = fmaxf((acc[m][t4][j] - mu)*rs*gwc[t4] + gbc[t4], 0.f);
      const int row = r0 + 16*m + 4*lg + j;
      #pragma unroll
      for (int t4 = 0; t4 < 8; ++t4) {
        const float oth = __shfl_xor(y[t4], 1);
        if ((t4 & 1) == (lr & 1)) {   // split the pair's 8 dwords: even lane
          const float lo = (lr & 1) ? oth : y[t4];      // even t4, odd lane
          const float hi = (lr & 1) ? y[t4] : oth;      // odd t4
          const unsigned int packed = ((unsigned int)f2bf(hi) << 16) | f2bf(lo);
          *(unsigned int*)&tempb[(size_t)row * NMC + 16*t4 + (lr & ~1)] = packed;
        }
      }
    }
  }
}

// ---------------------------------------------------------------------------
// k_combine: featb = bf16(relu(fi + fs));  fi in tempb, fs in featb.
// ---------------------------------------------------------------------------
__global__ __launch_bounds__(256) void k_combine(
    const __hip_bfloat16* __restrict__ fib, __hip_bfloat16* __restrict__ featb)
{
  int64_t i = (int64_t)blockIdx.x * blockDim.x + threadIdx.x;
  const int64_t total = (int64_t)NN * 64;
  const int64_t stride = (int64_t)gridDim.x * blockDim.x;
  for (; i < total; i += stride) {
    const unsigned int ap = ((const unsigned int*)fib)[i];
    const unsigned int bp = ((const unsigned int*)featb)[i];
    const float y0 = fmaxf(bf2f((unsigned short)(ap & 0xffff)) + bf2f((unsigned short)(bp & 0xffff)), 0.f);
    const float y1 = fmaxf(bf2f((unsigned short)(ap >> 16))    + bf2f((unsigned short)(bp >> 16)), 0.f);
    ((unsigned int*)featb)[i] = ((unsigned int)f2bf(y1) << 16) | f2bf(y0);
  }
}

// ---------------------------------------------------------------------------
extern "C" void kernel_launch(void* const* d_in, const int* in_sizes, int n_in,
                              void* d_out, int out_size, void* d_ws, size_t ws_size,
                              hipStream_t stream)
{
  const float* ctrs     = (const float*)d_in[0];
  const float* feats    = (const float*)d_in[1];
  const int*   pre_u    = (const int*)d_in[2];
  const int*   pre_v    = (const int*)d_in[3];
  const int*   suc_u    = (const int*)d_in[4];
  const int*   suc_v    = (const int*)d_in[5];
  const int*   left_u   = (const int*)d_in[6];
  const int*   left_v   = (const int*)d_in[7];
  const int*   right_u  = (const int*)d_in[8];
  const int*   right_v  = (const int*)d_in[9];
  const float* in1_w    = (const float*)d_in[10];
  const float* in1_b    = (const float*)d_in[11];
  const float* in2_w    = (const float*)d_in[12];
  const float* in_gn_w  = (const float*)d_in[13];
  const float* in_gn_b  = (const float*)d_in[14];
  const float* seg1_w   = (const float*)d_in[15];
  const float* seg1_b   = (const float*)d_in[16];
  const float* seg2_w   = (const float*)d_in[17];
  const float* seg_gn_w = (const float*)d_in[18];
  const float* seg_gn_b = (const float*)d_in[19];
  const float* ctr_w    = (const float*)d_in[20];
  const float* pre_w    = (const float*)d_in[21];
  const float* suc_w    = (const float*)d_in[22];
  const float* left_w   = (const float*)d_in[23];
  const float* right_w  = (const float*)d_in[24];
  const float* norm_w   = (const float*)d_in[25];
  const float* norm_b   = (const float*)d_in[26];
  const float* ctr2_w   = (const float*)d_in[27];
  const float* ctr2_gn_w= (const float*)d_in[28];
  const float* ctr2_gn_b= (const float*)d_in[29];

  // workspace layout (all offsets 256B-aligned)
  char* ws = (char*)d_ws;
  __hip_bfloat16* tempb = (__hip_bfloat16*)(ws);                 // 25,600,000
  __hip_bfloat16* featb = (__hip_bfloat16*)(ws + 25600000);      // 25,600,000
  __hip_bfloat16* Wb    = (__hip_bfloat16*)(ws + 51200000);      //  2,162,688
  int* cnt  = (int*)(ws + 53362688);                             //  5,600,000
  int* ofs  = (int*)(ws + 58962688);                             //  5,600,000
  int* vS   = (int*)(ws + 64562688);                             //  5,040,000
  int* btot = (int*)(ws + 69602688);                             //      3,584
  float* outf = (float*)d_out;

  // ---- weight pool conversion + CSR build (once per call) ----
  k_wconv<<<2048, 256, 0, stream>>>(in2_w, seg2_w, ctr_w, pre_w, suc_w,
                                    left_w, right_w, ctr2_w, Wb);
  hipMemsetAsync(cnt, 0, (size_t)14 * NN * 4, stream);
  k_hist<<<1232, 256, 0, stream>>>(pre_u, suc_u, left_u, right_u, cnt);
  k_scan1<<<14 * NSCB, 256, 0, stream>>>(cnt, ofs, btot);
  k_scan2<<<14, 64, 0, stream>>>(btot);
  k_scan3<<<2048, 256, 0, stream>>>(ofs, btot);
  k_scatter<<<1232, 256, 0, stream>>>(pre_u, suc_u, left_u, right_u,
                                      pre_v, suc_v, left_v, right_v, ofs, vS);

  // ---- stems ----
  k_stem1b<<<2048, 256, 0, stream>>>(ctrs, in1_w, in1_b, tempb);
  k_dense<1><<<625, 256, 0, stream>>>(tempb, Wb + 0*16384, tempb, nullptr,
                                      in_gn_w, in_gn_b, nullptr, 0);
  k_stem1b<<<2048, 256, 0, stream>>>(feats, seg1_w, seg1_b, featb);
  k_dense<1><<<625, 256, 0, stream>>>(featb, Wb + 1*16384, featb, nullptr,
                                      seg_gn_w, seg_gn_b, nullptr, 0);
  k_combine<<<2048, 256, 0, stream>>>(tempb, featb);

  // ---- fusion layers: 2 dispatches each ----
  for (int i = 0; i < LLAYERS; ++i) {
    k_layer<<<(NN/32 + 3)/4, 256, 0, stream>>>(featb, tempb, Wb, ofs, vS,
                                               norm_w + i*NMC, norm_b + i*NMC, i);
    k_dense<3><<<625, 256, 0, stream>>>(tempb, Wb + (size_t)(62+i)*16384,
                                        featb, outf,
                                        ctr2_gn_w + i*NMC, ctr2_gn_b + i*NMC,
                                        featb, (i == LLAYERS-1) ? 1 : 0);
  }
}